// Round 7
// baseline (198.139 us; speedup 1.0000x reference)
//
#include <hip/hip_runtime.h>
#include <hip/hip_cooperative_groups.h>

namespace cg = cooperative_groups;

// PiecewisePolynomial: out[b,o] = sum_i sum_j L_j(x_in(b,i)) * w[o, i, 3*seg(b,i)+j]
// B=512, IN_F=256, OUT_F=256, SEGMENTS=16, N=4 (nodes -1,-0.5,0.5,1)
//
// R7: ONE cooperative dispatch. Grid 256 (16 i-splits x 16 o-tiles, 1/CU) x 512.
// Stage w slice straight from global (w read once, no expand kernel, no we
// round-trip), f16 slot layout in 32KB LDS. Wave = 64 b rows, acc[16] over all
// 16 o. Partials (8.4MB, L3) -> grid.sync() -> fused coalesced reduce.

typedef _Float16 h2 __attribute__((ext_vector_type(2)));

#define INF     256
#define OUTF    256
#define WSTRIDE 49
#define OSTRIDE (INF * WSTRIDE)     // 12544
#define PSLICE  (512 * 256)         // floats per isplit partial slice

__global__ __launch_bounds__(512, 2)
void pp_fused(const float* __restrict__ x, const float* __restrict__ w,
              float* __restrict__ part, float* __restrict__ out) {
    // wt[16i][8op][16s] x uint4 {oe.p01, oe.p23, oo.p01, oo.p23} = 32 KB
    __shared__ unsigned int wt[8192];

    const int tid  = threadIdx.x;
    const int wave = tid >> 6, lane = tid & 63;
    const int isplit = blockIdx.x & 15;
    const int otile  = blockIdx.x >> 4;
    const int i_base = isplit * 16;
    const int o_base = otile * 16;
    const int b      = wave * 64 + lane;      // this lane's batch row

    // issue x loads first (consumed after the stage loop)
    const float4* xp = (const float4*)(x + (size_t)b * INF + i_base);
    float4 xv0 = xp[0], xv1 = xp[1], xv2 = xp[2], xv3 = xp[3];

    // ---- stage: w[o_base+o][i_base+i][t=lane] -> f16 slot layout (w read once) ----
    // row r = i*16+o; lane t<49 reads one float, writes 1-2 f16 halves:
    // (s1=t/3, j1=t%3) and, if t%3==0 && t>0, (s1-1, j=3) (shared node).
    _Float16* wth = (_Float16*)wt;
    for (int r = wave; r < 256; r += 8) {
        const int i_loc = r >> 4, o_loc = r & 15;
        const int op = o_loc >> 1, e = o_loc & 1;
        float v = 0.0f;
        if (lane < 49)
            v = w[(size_t)(o_base + o_loc) * OSTRIDE
                  + (size_t)(i_base + i_loc) * WSTRIDE + lane];
        const _Float16 hv = (_Float16)v;
        const int s1 = lane / 3, j1 = lane - 3 * s1;
        const int hb = (i_loc * 8 + op) * 16;          // uint4-row base (in s units)
        if (lane < 49) {
            if (s1 < 16)            wth[(hb + s1) * 8 + e * 4 + j1] = hv;
            if (j1 == 0 && lane)    wth[(hb + s1 - 1) * 8 + e * 4 + 3] = hv;
        }
    }

    // ---- per-lane basis + segment for own b, 16 i's (overlaps staging) ----
    float xs[16] = {xv0.x, xv0.y, xv0.z, xv0.w, xv1.x, xv1.y, xv1.z, xv1.w,
                    xv2.x, xv2.y, xv2.z, xv2.w, xv3.x, xv3.y, xv3.z, xv3.w};
    int sseg[16]; h2 cA[16], cB[16];
    #pragma unroll
    for (int i = 0; i < 16; ++i) {
        float xx = xs[i];
        int id = (int)((xx + 1.0f) * 8.0f);
        id = id < 0 ? 0 : (id > 15 ? 15 : id);
        float u = (xx - ((float)id * 0.125f - 1.0f)) * 16.0f - 1.0f;
        float a = u + 1.0f, b2 = u + 0.5f, cc = u - 0.5f, d = u - 1.0f;
        float c0 = b2 * cc * d  * (-2.0f / 3.0f);
        float c1 = a  * cc * d  * ( 4.0f / 3.0f);
        float c2 = a  * b2 * d  * (-4.0f / 3.0f);
        float c3 = a  * b2 * cc * ( 2.0f / 3.0f);
        h2 pA; pA[0] = (_Float16)c0; pA[1] = (_Float16)c1;
        h2 pB; pB[0] = (_Float16)c2; pB[1] = (_Float16)c3;
        cA[i] = pA; cB[i] = pB; sseg[i] = id;
    }

    __syncthreads();    // the one barrier: LDS weights valid

    // ---- compute: per i one seg-slot, 8 ds_read_b128 (o-pairs) + 32 fdot2 ----
    float acc[16];
    #pragma unroll
    for (int q = 0; q < 16; ++q) acc[q] = 0.0f;

    #pragma unroll
    for (int i = 0; i < 16; ++i) {
        const unsigned int* p = &wt[(i * 128 + sseg[i]) * 4];
        #pragma unroll
        for (int op = 0; op < 8; ++op) {
            uint4 v = *(const uint4*)(p + op * 64);
            acc[2*op]   = __builtin_amdgcn_fdot2(__builtin_bit_cast(h2, v.x), cA[i],
                                                 acc[2*op],   false);
            acc[2*op]   = __builtin_amdgcn_fdot2(__builtin_bit_cast(h2, v.y), cB[i],
                                                 acc[2*op],   false);
            acc[2*op+1] = __builtin_amdgcn_fdot2(__builtin_bit_cast(h2, v.z), cA[i],
                                                 acc[2*op+1], false);
            acc[2*op+1] = __builtin_amdgcn_fdot2(__builtin_bit_cast(h2, v.w), cB[i],
                                                 acc[2*op+1], false);
        }
    }

    // ---- partial store: 4 float4 per lane (same 64B line, L2 write-combined) ----
    {
        float4* pp = (float4*)(part + (size_t)isplit * PSLICE
                                    + (size_t)b * 256 + o_base);
        pp[0] = make_float4(acc[0],  acc[1],  acc[2],  acc[3]);
        pp[1] = make_float4(acc[4],  acc[5],  acc[6],  acc[7]);
        pp[2] = make_float4(acc[8],  acc[9],  acc[10], acc[11]);
        pp[3] = make_float4(acc[12], acc[13], acc[14], acc[15]);
    }

    __threadfence();
    cg::this_grid().sync();

    // ---- fused reduce: one out float per thread, coalesced over 16 slices ----
    const int idx = blockIdx.x * 512 + tid;     // 256*512 = 131072 = out size
    float s = 0.0f;
    #pragma unroll
    for (int k = 0; k < 16; ++k)
        s += part[(size_t)k * PSLICE + idx];
    out[idx] = s;
}

extern "C" void kernel_launch(void* const* d_in, const int* in_sizes, int n_in,
                              void* d_out, int out_size, void* d_ws, size_t ws_size,
                              hipStream_t stream) {
    const float* x = (const float*)d_in[0];
    const float* w = (const float*)d_in[1];
    float* out  = (float*)d_out;
    float* part = (float*)d_ws;                 // 16 x 512 x 256 x 4B = 8.4 MB
    (void)ws_size; (void)n_in; (void)in_sizes; (void)out_size;

    void* args[] = {(void*)&x, (void*)&w, (void*)&part, (void*)&out};
    hipLaunchCooperativeKernel(reinterpret_cast<void*>(pp_fused),
                               dim3(256), dim3(512), args, 0, stream);
}

// Round 8
// 87.718 us; speedup vs baseline: 2.2588x; 2.2588x over previous
//
#include <hip/hip_runtime.h>

// PiecewisePolynomial: out[b,o] = sum_i sum_j L_j(x_in(b,i)) * w[o, i, 3*seg(b,i)+j]
// B=512, IN_F=256, OUT_F=256, SEGMENTS=16, N=4 (nodes -1,-0.5,0.5,1)
//
// R8 = R7 without the cooperative grid sync (that was the 100 µs disease):
// two plain dispatches. pp_partial: grid 256 (16 i-splits x 16 o-tiles,
// 1 block/CU-sized, 2/CU resident) x 512 thr; stages its w slice DIRECTLY
// from w (read exactly once, no expand kernel) into a 32KB f16 slot-layout
// LDS tile; each wave owns 64 b rows; seg-indexed ds_read_b128 + fdot2 into
// acc[16]; partials (16 x 512 x 256 = 8.4MB, L3-resident). pp_reduce: float4
// sum over 16 slices.

typedef _Float16 h2 __attribute__((ext_vector_type(2)));

#define INF     256
#define OUTF    256
#define WSTRIDE 49
#define OSTRIDE (INF * WSTRIDE)     // 12544
#define PSLICE  (512 * 256)         // floats per isplit partial slice

__global__ __launch_bounds__(512, 2)
void pp_partial(const float* __restrict__ x, const float* __restrict__ w,
                float* __restrict__ part) {
    // wt[16i][8op][16s] x uint4 {oe.p01, oe.p23, oo.p01, oo.p23} = 32 KB
    __shared__ unsigned int wt[8192];

    const int tid  = threadIdx.x;
    const int wave = tid >> 6, lane = tid & 63;
    const int isplit = blockIdx.x & 15;
    const int otile  = blockIdx.x >> 4;
    const int i_base = isplit * 16;
    const int o_base = otile * 16;
    const int b      = wave * 64 + lane;      // this lane's batch row

    // issue x loads first (consumed after the stage loop)
    const float4* xp = (const float4*)(x + (size_t)b * INF + i_base);
    float4 xv0 = xp[0], xv1 = xp[1], xv2 = xp[2], xv3 = xp[3];

    // ---- stage: w[o_base+o][i_base+i][t=lane] -> f16 slot layout (w read once) --
    // row r = i*16+o; lane t<49 reads one float, writes 1-2 f16 halves:
    // (s1=t/3, j1=t%3) and, if t%3==0 && t>0, (s1-1, j=3) (shared node).
    _Float16* wth = (_Float16*)wt;
    for (int r = wave; r < 256; r += 8) {
        const int i_loc = r >> 4, o_loc = r & 15;
        const int op = o_loc >> 1, e = o_loc & 1;
        float v = 0.0f;
        if (lane < 49)
            v = w[(size_t)(o_base + o_loc) * OSTRIDE
                  + (size_t)(i_base + i_loc) * WSTRIDE + lane];
        const _Float16 hv = (_Float16)v;
        const int s1 = lane / 3, j1 = lane - 3 * s1;
        const int hb = (i_loc * 8 + op) * 16;          // uint4-row base (s units)
        if (lane < 49) {
            if (s1 < 16)            wth[(hb + s1) * 8 + e * 4 + j1] = hv;
            if (j1 == 0 && lane)    wth[(hb + s1 - 1) * 8 + e * 4 + 3] = hv;
        }
    }

    // ---- per-lane basis + segment for own b, 16 i's (overlaps staging) ----
    float xs[16] = {xv0.x, xv0.y, xv0.z, xv0.w, xv1.x, xv1.y, xv1.z, xv1.w,
                    xv2.x, xv2.y, xv2.z, xv2.w, xv3.x, xv3.y, xv3.z, xv3.w};
    int sseg[16]; h2 cA[16], cB[16];
    #pragma unroll
    for (int i = 0; i < 16; ++i) {
        float xx = xs[i];
        int id = (int)((xx + 1.0f) * 8.0f);
        id = id < 0 ? 0 : (id > 15 ? 15 : id);
        float u = (xx - ((float)id * 0.125f - 1.0f)) * 16.0f - 1.0f;
        float a = u + 1.0f, b2 = u + 0.5f, cc = u - 0.5f, d = u - 1.0f;
        float c0 = b2 * cc * d  * (-2.0f / 3.0f);
        float c1 = a  * cc * d  * ( 4.0f / 3.0f);
        float c2 = a  * b2 * d  * (-4.0f / 3.0f);
        float c3 = a  * b2 * cc * ( 2.0f / 3.0f);
        h2 pA; pA[0] = (_Float16)c0; pA[1] = (_Float16)c1;
        h2 pB; pB[0] = (_Float16)c2; pB[1] = (_Float16)c3;
        cA[i] = pA; cB[i] = pB; sseg[i] = id;
    }

    __syncthreads();    // the one barrier: LDS weights valid

    // ---- compute: per i one seg-slot, 8 ds_read_b128 (o-pairs) + 32 fdot2 ----
    float acc[16];
    #pragma unroll
    for (int q = 0; q < 16; ++q) acc[q] = 0.0f;

    #pragma unroll
    for (int i = 0; i < 16; ++i) {
        const unsigned int* p = &wt[(i * 128 + sseg[i]) * 4];
        #pragma unroll
        for (int op = 0; op < 8; ++op) {
            uint4 v = *(const uint4*)(p + op * 64);
            acc[2*op]   = __builtin_amdgcn_fdot2(__builtin_bit_cast(h2, v.x), cA[i],
                                                 acc[2*op],   false);
            acc[2*op]   = __builtin_amdgcn_fdot2(__builtin_bit_cast(h2, v.y), cB[i],
                                                 acc[2*op],   false);
            acc[2*op+1] = __builtin_amdgcn_fdot2(__builtin_bit_cast(h2, v.z), cA[i],
                                                 acc[2*op+1], false);
            acc[2*op+1] = __builtin_amdgcn_fdot2(__builtin_bit_cast(h2, v.w), cB[i],
                                                 acc[2*op+1], false);
        }
    }

    // ---- partial store: 4 float4 per lane (64B line, coalesced along o-tile) --
    float4* pp = (float4*)(part + (size_t)isplit * PSLICE
                                + (size_t)b * 256 + o_base);
    pp[0] = make_float4(acc[0],  acc[1],  acc[2],  acc[3]);
    pp[1] = make_float4(acc[4],  acc[5],  acc[6],  acc[7]);
    pp[2] = make_float4(acc[8],  acc[9],  acc[10], acc[11]);
    pp[3] = make_float4(acc[12], acc[13], acc[14], acc[15]);
}

__global__ __launch_bounds__(256)
void pp_reduce(const float* __restrict__ part, float* __restrict__ out) {
    const size_t off4 = (size_t)blockIdx.x * 256 + threadIdx.x;  // float4 idx
    const float4* p4 = (const float4*)part;
    float4 s = make_float4(0.f, 0.f, 0.f, 0.f);
    #pragma unroll
    for (int k = 0; k < 16; ++k) {
        float4 v = p4[(size_t)k * (PSLICE / 4) + off4];
        s.x += v.x; s.y += v.y; s.z += v.z; s.w += v.w;
    }
    ((float4*)out)[off4] = s;
}

extern "C" void kernel_launch(void* const* d_in, const int* in_sizes, int n_in,
                              void* d_out, int out_size, void* d_ws, size_t ws_size,
                              hipStream_t stream) {
    const float* x = (const float*)d_in[0];
    const float* w = (const float*)d_in[1];
    float* out  = (float*)d_out;
    float* part = (float*)d_ws;                 // 16 x 512 x 256 x 4B = 8.4 MB
    (void)ws_size; (void)n_in; (void)in_sizes; (void)out_size;

    pp_partial<<<dim3(256), 512, 0, stream>>>(x, w, part);
    pp_reduce<<<dim3(128), 256, 0, stream>>>(part, out);  // 128*256 float4 = out
}